// Round 2
// baseline (207.218 us; speedup 1.0000x reference)
//
#include <hip/hip_runtime.h>
#include <hip/hip_cooperative_groups.h>

namespace cg = cooperative_groups;

// Shapes (fixed by setup_inputs)
constexpr int N  = 4, C = 64, H = 16, W = 16;
constexpr int NF = 128;
constexpr int D  = C * 9;          // 576
constexpr float EPSF = 1e-5f;

// ---------------------------------------------------------------------------
// Fused kernel:
//   Phase A: s = conv3x3(x,w) in fp64; t = 2r/(2s+eps)           (per block:
//            8-wide ow strip x 64 filters; 1024 thr = f(64) x cg(16))
//   grid.sync()
//   Phase B: out = x * convT3x3(t, w)                            (per block:
//            8-wide w strip x 32 channels; 1024 thr = c(32) x fg(32))
//
// w is read DIRECTLY (no prep/repack kernel):
//   Phase A thread (f,cg) needs w[fh*64+f][cg*36 .. +35]: 9 aligned float4
//   (byte offset 2304*f + 144*cg + 16*i, all multiples of 16).
//   Phase B thread (c,fg) needs w[fg*4+j][(ch*32+c)*9 .. +8]: scalar loads.
//   (Round-1 bug: the ch*32 half-offset was dropped — fixed here.)
//
// LDS overlay (74752 B static, 1 block/CU):
//   A: xl  [C*36]  floats @0      (9216 B) | partd [16*8*64] doubles @9216 (64K)
//   B: tl  [NF*36] floats @0      (18432B) | fpart [32*8*32] floats @18432 (32K)
// ---------------------------------------------------------------------------
__global__ void __launch_bounds__(1024) k_fused(
        const float* __restrict__ x, const float* __restrict__ w,
        const float* __restrict__ r, float* __restrict__ t_g,
        float* __restrict__ out) {
    __shared__ __align__(16) unsigned char smem[74752];

    const int bid = blockIdx.x;
    const int tid = threadIdx.x;

    // ======================= Phase A: t = 2r/(2s+eps) =======================
    {
        float*  xl    = (float*)smem;            // [c][dh][12] (10 used)
        double* partd = (double*)(smem + 9216);  // [cg][o][f]

        const int fh  = bid & 1;
        const int ow0 = ((bid >> 1) & 1) * 8;
        const int oh  = (bid >> 2) & 15;
        const int n   = bid >> 6;
        const int f   = tid & 63;
        const int cgi = tid >> 6;                // 0..15

        // Direct per-lane w load: 9 aligned float4 = w[fh*64+f][cgi*36 .. +35]
        const float* __restrict__ wrow = w + (fh * 64 + f) * D + cgi * 36;
        float wreg[36];
#pragma unroll
        for (int i = 0; i < 9; ++i) {
            const float4 wv = *(const float4*)(wrow + i * 4);
            wreg[i * 4 + 0] = wv.x; wreg[i * 4 + 1] = wv.y;
            wreg[i * 4 + 2] = wv.z; wreg[i * 4 + 3] = wv.w;
        }

        // Stage x halo strip into LDS
        for (int idx = tid; idx < C * 30; idx += 1024) {
            const int c = idx / 30, rem = idx % 30;
            const int dh = rem / 10, dw = rem % 10;
            const int ih = oh - 1 + dh, iw = ow0 - 1 + dw;
            float v = 0.f;
            if (ih >= 0 && ih < H && iw >= 0 && iw < W)
                v = x[((n * C + c) * H + ih) * W + iw];
            xl[c * 36 + dh * 12 + dw] = v;
        }
        __syncthreads();

        const int c0 = cgi * 4;
        double acc[8];
#pragma unroll
        for (int o = 0; o < 8; ++o) acc[o] = 0.0;

#pragma unroll
        for (int cl = 0; cl < 4; ++cl) {
#pragma unroll
            for (int dh = 0; dh < 3; ++dh) {
                const float* rowp = xl + (c0 + cl) * 36 + dh * 12;
                const float4 xa = *(const float4*)rowp;
                const float4 xb = *(const float4*)(rowp + 4);
                const float2 xc = *(const float2*)(rowp + 8);
                double xd[10];
                xd[0] = (double)xa.x; xd[1] = (double)xa.y;
                xd[2] = (double)xa.z; xd[3] = (double)xa.w;
                xd[4] = (double)xb.x; xd[5] = (double)xb.y;
                xd[6] = (double)xb.z; xd[7] = (double)xb.w;
                xd[8] = (double)xc.x; xd[9] = (double)xc.y;
#pragma unroll
                for (int b = 0; b < 3; ++b) {
                    const double wd = (double)wreg[cl * 9 + dh * 3 + b];
#pragma unroll
                    for (int o = 0; o < 8; ++o)
                        acc[o] += wd * xd[b + o];
                }
            }
        }

#pragma unroll
        for (int o = 0; o < 8; ++o)
            partd[(cgi * 8 + o) * 64 + f] = acc[o];
        __syncthreads();

        if (tid < 512) {
            const int f2 = tid & 63, o = tid >> 6;
            double s = 0.0;
#pragma unroll
            for (int g = 0; g < 16; ++g)
                s += partd[(g * 8 + o) * 64 + f2];
            const int fglob = fh * 64 + f2;
            const int idx = ((n * NF + fglob) * H + oh) * W + ow0 + o;
            t_g[idx] = (float)((2.0 * (double)r[idx]) / (2.0 * s + (double)EPSF));
        }
    }

    __threadfence();          // agent-scope release of t_g (cross-XCD safety)
    cg::this_grid().sync();

    // ==================== Phase B: out = x * convT(t,w) =====================
    {
        float* tl    = (float*)smem;             // [f][a][12] (10 used)
        float* fpart = (float*)(smem + 18432);   // [fg][o][c]

        const int ch = bid & 1;
        const int w0 = ((bid >> 1) & 1) * 8;
        const int h  = (bid >> 2) & 15;
        const int n  = bid >> 6;
        const int c  = tid & 31;
        const int fg = tid >> 5;                 // 0..31

        // Stage t halo strip into LDS
        for (int idx = tid; idx < NF * 30; idx += 1024) {
            const int ff = idx / 30, rem = idx % 30;
            const int a = rem / 10, ww = rem % 10;
            const int oh2 = h - 1 + a, ow = w0 - 1 + ww;
            float v = 0.f;
            if (oh2 >= 0 && oh2 < H && ow >= 0 && ow < W)
                v = t_g[((n * NF + ff) * H + oh2) * W + ow];
            tl[ff * 36 + a * 12 + ww] = v;
        }

        // Direct per-lane w load: rows fg*4+j, cols (ch*32+c)*9 .. +8
        float wr2[36];
#pragma unroll
        for (int j = 0; j < 4; ++j) {
            const float* __restrict__ wp = w + (fg * 4 + j) * D + (ch * 32 + c) * 9;
#pragma unroll
            for (int k = 0; k < 9; ++k)
                wr2[j * 9 + k] = wp[k];
        }
        __syncthreads();

        float acc[8];
#pragma unroll
        for (int o = 0; o < 8; ++o) acc[o] = 0.f;

#pragma unroll
        for (int j = 0; j < 4; ++j) {
            const int fi = fg * 4 + j;
#pragma unroll
            for (int a = 0; a < 3; ++a) {
                const float* rowp = tl + fi * 36 + a * 12;
                const float4 ta = *(const float4*)rowp;
                const float4 tb = *(const float4*)(rowp + 4);
                const float2 tc = *(const float2*)(rowp + 8);
                const float tw[10] = {ta.x, ta.y, ta.z, ta.w,
                                      tb.x, tb.y, tb.z, tb.w, tc.x, tc.y};
#pragma unroll
                for (int b = 0; b < 3; ++b) {
                    // adjoint (fold) uses flipped taps
                    const float wv = wr2[j * 9 + (2 - a) * 3 + (2 - b)];
#pragma unroll
                    for (int o = 0; o < 8; ++o)
                        acc[o] += wv * tw[b + o];
                }
            }
        }

#pragma unroll
        for (int o = 0; o < 8; ++o)
            fpart[(fg * 8 + o) * 32 + c] = acc[o];
        __syncthreads();

        if (tid < 256) {
            const int c2 = tid & 31, o = tid >> 5;
            float s = 0.f;
#pragma unroll
            for (int g = 0; g < 32; ++g)
                s += fpart[(g * 8 + o) * 32 + c2];
            const int cglob = ch * 32 + c2;
            const int idx = ((n * C + cglob) * H + h) * W + w0 + o;
            out[idx] = x[idx] * s;
        }
    }
}

// ---------------------------------------------------------------------------
extern "C" void kernel_launch(void* const* d_in, const int* in_sizes, int n_in,
                              void* d_out, int out_size, void* d_ws, size_t ws_size,
                              hipStream_t stream) {
    const float* x = (const float*)d_in[0];   // (4,64,16,16)
    const float* r = (const float*)d_in[1];   // (4,128,16,16)
    const float* w = (const float*)d_in[2];   // (128,64,3,3)
    float* out = (float*)d_out;               // (4,64,16,16)
    float* t_g = (float*)d_ws;                // 131072 floats

    void* args[] = { (void*)&x, (void*)&w, (void*)&r, (void*)&t_g, (void*)&out };
    hipLaunchCooperativeKernel((void*)k_fused, dim3(256), dim3(1024),
                               args, 0, stream);
}

// Round 3
// 73.363 us; speedup vs baseline: 2.8246x; 2.8246x over previous
//
#include <hip/hip_runtime.h>

// Shapes (fixed by setup_inputs)
constexpr int N  = 4, C = 64, H = 16, W = 16;
constexpr int NF = 128;
constexpr int D  = C * 9;          // 576
constexpr float EPSF = 1e-5f;

// ---------------------------------------------------------------------------
// K1: s = conv3x3(x,w) fp64; t = 2r/(2s+eps)
// Grid 256 = (n4, oh16, owg2, fhalf2): block does 8-wide ow strip x 64 filters.
// Threads 1024 = f(64) x cg(16); cg owns 4 channels.
// w read DIRECTLY: thread (f,cg) loads w[fh*64+f][cg*36 .. +35] as 9 aligned
// float4 (byte offset 2304*f + 144*cg, all multiples of 16).  No prep kernel.
// x staged fp32 [c][dh][12] (aligned rows); partials partd[cg][o][f].
// ---------------------------------------------------------------------------
__global__ void __launch_bounds__(1024) k_conv_t(
        const float* __restrict__ x, const float* __restrict__ w,
        const float* __restrict__ r, float* __restrict__ t_g) {
    __shared__ float  xl[C * 36];           // 9.2 KB: [c][dh][12] (10 used)
    __shared__ double partd[16 * 8 * 64];   // 64 KB: [cg][o][f]

    const int bid = blockIdx.x;
    const int fh  = bid & 1;
    const int ow0 = ((bid >> 1) & 1) * 8;
    const int oh  = (bid >> 2) & 15;
    const int n   = bid >> 6;
    const int tid = threadIdx.x;
    const int f   = tid & 63;
    const int cgi = tid >> 6;               // 0..15

    // Direct per-lane w load (issue before staging so latency overlaps)
    const float* __restrict__ wrow = w + (fh * 64 + f) * D + cgi * 36;
    float wreg[36];
#pragma unroll
    for (int i = 0; i < 9; ++i) {
        const float4 wv = *(const float4*)(wrow + i * 4);
        wreg[i * 4 + 0] = wv.x; wreg[i * 4 + 1] = wv.y;
        wreg[i * 4 + 2] = wv.z; wreg[i * 4 + 3] = wv.w;
    }

    for (int idx = tid; idx < C * 30; idx += 1024) {
        const int c = idx / 30, rem = idx % 30;
        const int dh = rem / 10, dw = rem % 10;
        const int ih = oh - 1 + dh, iw = ow0 - 1 + dw;
        float v = 0.f;
        if (ih >= 0 && ih < H && iw >= 0 && iw < W)
            v = x[((n * C + c) * H + ih) * W + iw];
        xl[c * 36 + dh * 12 + dw] = v;
    }
    __syncthreads();

    const int c0 = cgi * 4;
    double acc[8];
#pragma unroll
    for (int o = 0; o < 8; ++o) acc[o] = 0.0;

#pragma unroll
    for (int cl = 0; cl < 4; ++cl) {
#pragma unroll
        for (int dh = 0; dh < 3; ++dh) {
            const float* rowp = xl + (c0 + cl) * 36 + dh * 12;
            const float4 xa = *(const float4*)rowp;
            const float4 xb = *(const float4*)(rowp + 4);
            const float2 xc = *(const float2*)(rowp + 8);
            double xd[10];
            xd[0] = (double)xa.x; xd[1] = (double)xa.y;
            xd[2] = (double)xa.z; xd[3] = (double)xa.w;
            xd[4] = (double)xb.x; xd[5] = (double)xb.y;
            xd[6] = (double)xb.z; xd[7] = (double)xb.w;
            xd[8] = (double)xc.x; xd[9] = (double)xc.y;
#pragma unroll
            for (int b = 0; b < 3; ++b) {
                const double wd = (double)wreg[cl * 9 + dh * 3 + b];
#pragma unroll
                for (int o = 0; o < 8; ++o)
                    acc[o] += wd * xd[b + o];
            }
        }
    }

#pragma unroll
    for (int o = 0; o < 8; ++o)
        partd[(cgi * 8 + o) * 64 + f] = acc[o];
    __syncthreads();

    if (tid < 512) {
        const int f2 = tid & 63, o = tid >> 6;
        double s = 0.0;
#pragma unroll
        for (int g = 0; g < 16; ++g)
            s += partd[(g * 8 + o) * 64 + f2];
        const int fglob = fh * 64 + f2;
        const int idx = ((n * NF + fglob) * H + oh) * W + ow0 + o;
        t_g[idx] = (float)((2.0 * (double)r[idx]) / (2.0 * s + (double)EPSF));
    }
}

// ---------------------------------------------------------------------------
// K2: out = x * convT3x3(t, w)
// Grid 256 = (n4, h16, wg2, chalf2): block does 8-wide w strip x 32 channels.
// Threads 1024 = c(32) x fg(32); fg owns 4 filters.
// w read DIRECTLY: thread (c,fg) loads w[fg*4+j][(ch*32+c)*9 .. +8], j=0..3
// (scalar loads; flip applied at use site).  No prep kernel.
// t staged [f][a][12] aligned; partials fpart[fg][o][c].
// ---------------------------------------------------------------------------
__global__ void __launch_bounds__(1024) k_convT_out(
        const float* __restrict__ x, const float* __restrict__ w,
        const float* __restrict__ t_g, float* __restrict__ out) {
    __shared__ float tl[NF * 36];           // 18.4 KB: [f][a][12] (10 used)
    __shared__ float fpart[32 * 8 * 32];    // 32.8 KB: [fg][o][c]

    const int bid = blockIdx.x;
    const int ch  = bid & 1;
    const int w0  = ((bid >> 1) & 1) * 8;
    const int h   = (bid >> 2) & 15;
    const int n   = bid >> 6;
    const int tid = threadIdx.x;
    const int c   = tid & 31;
    const int fg  = tid >> 5;               // 0..31

    // Direct per-lane w load (issue before staging so latency overlaps)
    float wr2[36];
#pragma unroll
    for (int j = 0; j < 4; ++j) {
        const float* __restrict__ wp = w + (fg * 4 + j) * D + (ch * 32 + c) * 9;
#pragma unroll
        for (int k = 0; k < 9; ++k)
            wr2[j * 9 + k] = wp[k];
    }

    for (int idx = tid; idx < NF * 30; idx += 1024) {
        const int ff = idx / 30, rem = idx % 30;
        const int a = rem / 10, ww = rem % 10;
        const int oh2 = h - 1 + a, ow = w0 - 1 + ww;
        float v = 0.f;
        if (oh2 >= 0 && oh2 < H && ow >= 0 && ow < W)
            v = t_g[((n * NF + ff) * H + oh2) * W + ow];
        tl[ff * 36 + a * 12 + ww] = v;
    }
    __syncthreads();

    float acc[8];
#pragma unroll
    for (int o = 0; o < 8; ++o) acc[o] = 0.f;

#pragma unroll
    for (int j = 0; j < 4; ++j) {
        const int fi = fg * 4 + j;
#pragma unroll
        for (int a = 0; a < 3; ++a) {
            const float* rowp = tl + fi * 36 + a * 12;
            const float4 ta = *(const float4*)rowp;
            const float4 tb = *(const float4*)(rowp + 4);
            const float2 tc = *(const float2*)(rowp + 8);
            const float tw[10] = {ta.x, ta.y, ta.z, ta.w,
                                  tb.x, tb.y, tb.z, tb.w, tc.x, tc.y};
#pragma unroll
            for (int b = 0; b < 3; ++b) {
                // adjoint (fold) uses flipped taps
                const float wv = wr2[j * 9 + (2 - a) * 3 + (2 - b)];
#pragma unroll
                for (int o = 0; o < 8; ++o)
                    acc[o] += wv * tw[b + o];
            }
        }
    }

#pragma unroll
    for (int o = 0; o < 8; ++o)
        fpart[(fg * 8 + o) * 32 + c] = acc[o];
    __syncthreads();

    if (tid < 256) {
        const int c2 = tid & 31, o = tid >> 5;
        float s = 0.f;
#pragma unroll
        for (int g = 0; g < 32; ++g)
            s += fpart[(g * 8 + o) * 32 + c2];
        const int cglob = ch * 32 + c2;
        const int idx = ((n * C + cglob) * H + h) * W + w0 + o;
        out[idx] = x[idx] * s;
    }
}

// ---------------------------------------------------------------------------
extern "C" void kernel_launch(void* const* d_in, const int* in_sizes, int n_in,
                              void* d_out, int out_size, void* d_ws, size_t ws_size,
                              hipStream_t stream) {
    const float* x = (const float*)d_in[0];   // (4,64,16,16)
    const float* r = (const float*)d_in[1];   // (4,128,16,16)
    const float* w = (const float*)d_in[2];   // (128,64,3,3)
    float* out = (float*)d_out;               // (4,64,16,16)
    float* t_g = (float*)d_ws;                // 131072 floats

    k_conv_t<<<256, 1024, 0, stream>>>(x, w, r, t_g);
    k_convT_out<<<256, 1024, 0, stream>>>(x, w, t_g, out);
}